// Round 1
// 206.554 us; speedup vs baseline: 1.0582x; 1.0582x over previous
//
#include <hip/hip_runtime.h>
#include <hip/hip_fp16.h>

// Problem constants
#define S_LEN 128
#define DLOG  128
#define DMEM  16
#define SO    120
#define HDIM  256

typedef _Float16 v8h __attribute__((ext_vector_type(8)));
typedef __fp16 v2hf __attribute__((ext_vector_type(2)));
typedef float v4f __attribute__((ext_vector_type(4)));

union PkU { v2hf h; unsigned u; };
union V8U { v8h v; int u[4]; };

__device__ __forceinline__ v8h splat8(float x) {
  _Float16 h = (_Float16)x;
  v8h v = {h, h, h, h, h, h, h, h};
  return v;
}

// ---------------------------------------------------------------------------
// K1: Q = x@Wq^T + bq,  K = x@Wk^T + bk   (tiny)
// ---------------------------------------------------------------------------
__global__ __launch_bounds__(128) void qk_kernel(
    const float* __restrict__ xl, const float* __restrict__ Wq,
    const float* __restrict__ bq, const float* __restrict__ Wk,
    const float* __restrict__ bk, float* __restrict__ Q, float* __restrict__ K) {
  int bj = blockIdx.x, o = threadIdx.x;
  __shared__ float xs[128];
  xs[o] = xl[bj * 128 + o];
  __syncthreads();
  float aq = bq[o], ak = bk[o];
  const float* wq = Wq + o * 128;
  const float* wk = Wk + o * 128;
  #pragma unroll 4
  for (int d = 0; d < 128; ++d) {
    float x = xs[d];
    aq = fmaf(x, wq[d], aq);
    ak = fmaf(x, wk[d], ak);
  }
  Q[bj * 128 + o] = aq;
  K[bj * 128 + o] = ak;
}

// ---------------------------------------------------------------------------
// K2: attn[b,j,i] = softmax_i( Q[b,j].K[b,i] / sqrt(128) )
// ---------------------------------------------------------------------------
__global__ __launch_bounds__(128) void attn_kernel(
    const float* __restrict__ Q, const float* __restrict__ K,
    float* __restrict__ attn) {
  int bj = blockIdx.x, b = bj >> 7, i = threadIdx.x;
  __shared__ float qs[128];
  __shared__ float red[128];
  qs[i] = Q[bj * 128 + i];
  __syncthreads();
  const float* kr = K + (b * 128 + i) * 128;
  float s = 0.f;
  #pragma unroll 4
  for (int d = 0; d < 128; ++d) s = fmaf(qs[d], kr[d], s);
  s *= 0.08838834764831845f;  // 1/sqrt(128)
  red[i] = s;
  __syncthreads();
  for (int off = 64; off; off >>= 1) {
    if (i < off) red[i] = fmaxf(red[i], red[i + off]);
    __syncthreads();
  }
  float m = red[0];
  __syncthreads();
  float e = expf(s - m);
  red[i] = e;
  __syncthreads();
  for (int off = 64; off; off >>= 1) {
    if (i < off) red[i] += red[i + off];
    __syncthreads();
  }
  attn[(size_t)bj * 128 + i] = e / red[0];
}

// ---------------------------------------------------------------------------
// K3 (MFMA): h[p][o] = tanh(delta[p].W1[o] + b1[o]), stored f16 in the first
// 512 B of pair p's 1024-B T-slot.
// ---------------------------------------------------------------------------
__global__ __launch_bounds__(256) void h_kernel(
    const float* __restrict__ xl, const float* __restrict__ W1,
    const float* __restrict__ b1, __half* __restrict__ hG) {
  __shared__ _Float16 w1s[128 * 136];
  __shared__ _Float16 dstage[64 * 136];
  __shared__ float xjs[128];
  int t = threadIdx.x;
  int blk = blockIdx.x;
  int bj = blk >> 1;   // 0..511
  int oh = blk & 1;    // o-half
  int b = bj >> 7;
  int o0 = oh * 128;

  if (t < 128) xjs[t] = xl[bj * 128 + t];
  for (int idx = t; idx < 128 * 128; idx += 256) {
    int o = idx >> 7, k = idx & 127;
    w1s[o * 136 + k] = (_Float16)W1[(o0 + o) * 128 + k];
  }
  __syncthreads();

  int lane = t & 63, w = t >> 6;
  int nn = lane & 15, q = lane >> 4;
  int ow = o0 + w * 32;
  float bb0 = b1[ow + nn], bb1 = b1[ow + 16 + nn];
  const float* xb = xl + (size_t)b * 128 * 128;

  for (int pi = 0; pi < 2; ++pi) {
    for (int idx = t; idx < 64 * 128; idx += 256) {
      int i = idx >> 7, k = idx & 127;
      dstage[i * 136 + k] = (_Float16)(xjs[k] - xb[(pi * 64 + i) * 128 + k]);
    }
    __syncthreads();

    v4f acc[4][2];
    #pragma unroll
    for (int mi = 0; mi < 4; ++mi) {
      acc[mi][0] = (v4f){0.f, 0.f, 0.f, 0.f};
      acc[mi][1] = (v4f){0.f, 0.f, 0.f, 0.f};
    }
    #pragma unroll
    for (int ks = 0; ks < 4; ++ks) {
      v8h bf0 = *(const v8h*)&w1s[(w * 32 + nn) * 136 + ks * 32 + q * 8];
      v8h bf1 = *(const v8h*)&w1s[(w * 32 + 16 + nn) * 136 + ks * 32 + q * 8];
      #pragma unroll
      for (int mi = 0; mi < 4; ++mi) {
        v8h af = *(const v8h*)&dstage[(mi * 16 + nn) * 136 + ks * 32 + q * 8];
        acc[mi][0] = __builtin_amdgcn_mfma_f32_16x16x32_f16(af, bf0, acc[mi][0], 0, 0, 0);
        acc[mi][1] = __builtin_amdgcn_mfma_f32_16x16x32_f16(af, bf1, acc[mi][1], 0, 0, 0);
      }
    }
    #pragma unroll
    for (int mi = 0; mi < 4; ++mi) {
      #pragma unroll
      for (int nt = 0; nt < 2; ++nt) {
        int o = ow + nt * 16 + nn;
        float bbv = nt ? bb1 : bb0;
        #pragma unroll
        for (int reg = 0; reg < 4; ++reg) {
          int i = pi * 64 + mi * 16 + 4 * q + reg;
          float x = acc[mi][nt][reg] + bbv;
          float ax = fabsf(x);
          float e = __expf(-2.f * ax);
          float r = __fdividef(1.f - e, 1.f + e);
          r = copysignf(r, x);
          hG[(size_t)(bj * 128 + i) * 512 + o] = __float2half(r);
        }
      }
    }
    __syncthreads();
  }
}

// ---------------------------------------------------------------------------
// K4a: lie[p][n] = h[p] . W2[n] + b2[n], f16 MFMA GEMM (M=pairs, N=120pad128,
// K=256). h read f16 from slot bytes [0,512); lie written f16 to slot bytes
// [512,752). 64 pairs/block, W2 staged in two K-halves.
// ---------------------------------------------------------------------------
__global__ __launch_bounds__(256) void lie_kernel(
    const float* __restrict__ W2g, const float* __restrict__ b2g,
    float* __restrict__ Tg) {
  __shared__ _Float16 w2t[128 * 136];
  int t = threadIdx.x, lane = t & 63;
  int wu = __builtin_amdgcn_readfirstlane(t >> 6);
  int pbase = blockIdx.x * 64 + wu * 16;
  int nn = lane & 15, q = lane >> 4;
  const _Float16* hf = (const _Float16*)Tg;

  v4f acc[8];
  #pragma unroll
  for (int tt = 0; tt < 8; ++tt) acc[tt] = (v4f){0.f, 0.f, 0.f, 0.f};

  const _Float16* hrow = hf + (size_t)(pbase + nn) * 512;
  for (int khalf = 0; khalf < 2; ++khalf) {
    __syncthreads();
    for (int idx = t; idx < 120 * 128; idx += 256) {
      int o = idx >> 7, kk = idx & 127;
      w2t[o * 136 + kk] = (_Float16)W2g[o * 256 + khalf * 128 + kk];
    }
    for (int idx = t; idx < 8 * 128; idx += 256)
      w2t[(120 + (idx >> 7)) * 136 + (idx & 127)] = (_Float16)0.f;
    __syncthreads();
    #pragma unroll
    for (int ks = 0; ks < 4; ++ks) {
      v8h ah = *(const v8h*)(hrow + khalf * 128 + ks * 32 + 8 * q);
      #pragma unroll
      for (int tt = 0; tt < 8; ++tt) {
        const v8h bf = *(const v8h*)(w2t + (16 * tt + nn) * 136 + ks * 32 + 8 * q);
        acc[tt] = __builtin_amdgcn_mfma_f32_16x16x32_f16(ah, bf, acc[tt], 0, 0, 0);
      }
    }
  }

  _Float16* hw = (_Float16*)Tg;
  #pragma unroll
  for (int tt = 0; tt < 8; ++tt) {
    int n16 = 16 * tt + nn;
    if (n16 < 120) {
      float bb = b2g[n16];
      #pragma unroll
      for (int reg = 0; reg < 4; ++reg) {
        size_t p = (size_t)(pbase + 4 * q + reg);
        hw[p * 512 + 256 + n16] = (_Float16)(acc[tt][reg] + bb);
      }
    }
  }
}

// ---------------------------------------------------------------------------
// K4b: per-pair T = expm(skew(lie)) via Paterson-Stockmeyer even/odd split:
//   exp(A) = C(B) + A*Q(B),  B = A^2 (SYMMETRIC -> one bpermute transform
//   serves as BOTH MFMA operands).
//   C = I + B/2 + B^2/24 + B^3/720 + B^4/40320
//   Q = I + B/6 + B^2/120 + B^3/5040 + B^4/362880
// Same degree-9 Taylor polynomial as before, but 5 MFMAs + 3 transforms
// instead of 8 MFMAs + 7 transforms. Combos (c4*B^2+c3*B+c2*I) are formed in
// the f16 frag domain with packed f16 FMAs; low-order terms (I, A, B/2, B/6)
// stay f32-exact. Squaring path unchanged.
// Epilogue additionally computes the attn-weighted transported vector and
// writes per-block partial settled sums (fuses old settle_kernel's 64 MB
// T re-read away).
// ---------------------------------------------------------------------------
__device__ __forceinline__ void split8(const float* x, v8h& hi, v8h& lo) {
  union U { v8h v; v2hf p[4]; } H, L;
  #pragma unroll
  for (int i = 0; i < 4; ++i) {
    float a = x[2 * i], b = x[2 * i + 1];
    v2hf h = __builtin_amdgcn_cvt_pkrtz(a, b);
    float ra = (float)h[0], rb = (float)h[1];
    v2hf l = __builtin_amdgcn_cvt_pkrtz(a - ra, b - rb);
    H.p[i] = h;
    L.p[i] = l;
  }
  hi = H.v;
  lo = L.v;
}

__device__ __forceinline__ int lie_idx(int rr, int cc) {
  return 15 * rr - ((rr * (rr - 1)) >> 1) + cc - rr - 1;
}

__global__ __launch_bounds__(256) void expm_kernel(
    float* __restrict__ Tg, const float* __restrict__ attn,
    const float* __restrict__ xm, float* __restrict__ part) {
  __shared__ char lds[12288] __attribute__((aligned(16)));
  __shared__ float sred[4][16];
  int t = threadIdx.x, lane = t & 63;
  int wu = __builtin_amdgcn_readfirstlane(t >> 6);
  int pbase = blockIdx.x * 8 + wu * 2;
  int nn = lane & 15, q = lane >> 4, b8 = (q & 1) * 8;
  char* wb = lds + wu * 3072;
  _Float16* lieS = (_Float16*)wb;   // [2][128] f16
  float* ErB = (float*)(wb + 512);  // [2][320] f32 (16 rows x stride 20)
  const _Float16* hf = (const _Float16*)Tg;

  // bpermute source lanes for the C-layout -> gather-layout transform:
  // requester (q,nn) needs regs of lanes 16*(2*(q&1))+nn and +16.
  int idxA = ((2 * (q & 1)) * 16 + nn) * 4;
  int idxB = idxA + 64;

  // ---- load lie, compute per-pair scaling ----
  float scv[2];
  int sv[2];
  #pragma unroll
  for (int j = 0; j < 2; ++j) {
    size_t p = (size_t)(pbase + j);
    _Float16 a0 = (lane < 120) ? hf[p * 512 + 256 + lane] : (_Float16)0.f;
    _Float16 a1 = (lane < 56) ? hf[p * 512 + 320 + lane] : (_Float16)0.f;
    lieS[j * 128 + lane] = a0;
    lieS[j * 128 + 64 + lane] = a1;
    float f0 = (float)a0, f1 = (float)a1;
    float s2 = f0 * f0 + f1 * f1;
    #pragma unroll
    for (int off = 1; off < 64; off <<= 1) s2 += __shfl_xor(s2, off, 64);
    float bound = sqrtf(s2);  // ||A||_2 <= sqrt(sum lie^2) for skew
    int s = 0;
    while (bound > 1.0f && s < 12) { bound *= 0.5f; s++; }
    sv[j] = __builtin_amdgcn_readfirstlane(s);
    scv[j] = ldexpf(1.0f, -s);
  }
  asm volatile("s_waitcnt lgkmcnt(0)" ::: "memory");

  // ---- A-frags (f16-exact, [X|X] dup) + f32 C-layout rows of A ----
  V8U Apk[2], BfA[2];
  v4f Af[2];
  #pragma unroll
  for (int j = 0; j < 2; ++j) {
    const _Float16* lp = lieS + j * 128;
    float sc = scv[j];
    float av[8];
    #pragma unroll
    for (int jj = 0; jj < 8; ++jj) {
      int c = b8 + jj;
      int rr = min(nn, c), c2 = max(nn, c);
      float lv = (c == nn) ? 0.f : (float)lp[lie_idx(rr, c2)];
      av[jj] = (c == nn) ? 0.f : ((c > nn) ? lv : -lv) * sc;
    }
    #pragma unroll
    for (int i = 0; i < 4; ++i) {
      PkU u;
      u.h = __builtin_amdgcn_cvt_pkrtz(av[2 * i], av[2 * i + 1]);
      Apk[j].u[i] = (int)u.u;
      BfA[j].u[i] = Apk[j].u[i] ^ 0x80008000;  // B-frag of A (= -A rows)
    }
    #pragma unroll
    for (int reg = 0; reg < 4; ++reg) {
      int r = 4 * q + reg;
      int rr = min(r, nn), c2 = max(r, nn);
      float lv = (r == nn) ? 0.f : (float)lp[lie_idx(rr, c2)];
      Af[j][reg] = (r == nn) ? 0.f : ((nn > r) ? lv : -lv) * sc;
    }
  }

  // identity frags in gather layout, pre-scaled by combo coefficients
  V8U IC1, IC2;
  #pragma unroll
  for (int i = 0; i < 4; ++i) {
    float d0 = (b8 + 2 * i == nn) ? 1.f : 0.f;
    float d1 = (b8 + 2 * i + 1 == nn) ? 1.f : 0.f;
    PkU u1, u2;
    u1.h = __builtin_amdgcn_cvt_pkrtz(10.666667f * d0, 10.666667f * d1);   // 256/24
    u2.h = __builtin_amdgcn_cvt_pkrtz(2.1333333f * d0, 2.1333333f * d1);   // 256/120
    IC1.u[i] = (int)u1.u;
    IC2.u[i] = (int)u2.u;
  }

  v4f z4 = {0.f, 0.f, 0.f, 0.f};

  // ---- MFMA1: cB = 2*B (B = A^2) ----
  v4f cB[2];
  #pragma unroll
  for (int j = 0; j < 2; ++j)
    cB[j] = __builtin_amdgcn_mfma_f32_16x16x32_f16(Apk[j].v, BfA[j].v, z4, 0, 0, 0);

  // ---- transform 1: fB = gather(2B)  (symmetric -> both-operand frag) ----
  V8U fB[2];
  #pragma unroll
  for (int j = 0; j < 2; ++j) {
    PkU u0, u1;
    u0.h = __builtin_amdgcn_cvt_pkrtz(cB[j][0], cB[j][1]);
    u1.h = __builtin_amdgcn_cvt_pkrtz(cB[j][2], cB[j][3]);
    fB[j].u[0] = __builtin_amdgcn_ds_bpermute(idxA, (int)u0.u);
    fB[j].u[1] = __builtin_amdgcn_ds_bpermute(idxA, (int)u1.u);
    fB[j].u[2] = __builtin_amdgcn_ds_bpermute(idxB, (int)u0.u);
    fB[j].u[3] = __builtin_amdgcn_ds_bpermute(idxB, (int)u1.u);
  }

  // ---- MFMA2: cB2 = 8*B^2 ----
  v4f cB2[2];
  #pragma unroll
  for (int j = 0; j < 2; ++j)
    cB2[j] = __builtin_amdgcn_mfma_f32_16x16x32_f16(fB[j].v, fB[j].v, z4, 0, 0, 0);

  // ---- transform 2: fB2 = gather(8*B^2) ----
  V8U fB2[2];
  #pragma unroll
  for (int j = 0; j < 2; ++j) {
    PkU u0, u1;
    u0.h = __builtin_amdgcn_cvt_pkrtz(cB2[j][0], cB2[j][1]);
    u1.h = __builtin_amdgcn_cvt_pkrtz(cB2[j][2], cB2[j][3]);
    fB2[j].u[0] = __builtin_amdgcn_ds_bpermute(idxA, (int)u0.u);
    fB2[j].u[1] = __builtin_amdgcn_ds_bpermute(idxA, (int)u1.u);
    fB2[j].u[2] = __builtin_amdgcn_ds_bpermute(idxB, (int)u0.u);
    fB2[j].u[3] = __builtin_amdgcn_ds_bpermute(idxB, (int)u1.u);
  }

  // ---- combo frags (packed f16 FMAs): M1 = 256*(c4 B^2 + c3 B + c2 I),
  //      M2 = 256*(q4 B^2 + q3 B + q2 I), expressed via fB (=2B), fB2 (=8B^2)
  v8h k1a = splat8(7.9365079e-4f);   // 256*c4/8 = 32/40320
  v8h k1b = splat8(0.17777778f);     // 256*c3/2 = 128/720
  v8h k2a = splat8(8.8183422e-5f);   // 256*q4/8 = 32/362880
  v8h k2b = splat8(2.5396825e-2f);   // 256*q3/2 = 128/5040
  V8U M1[2], M2[2];
  #pragma unroll
  for (int j = 0; j < 2; ++j) {
    M1[j].v = fB2[j].v * k1a + (fB[j].v * k1b + IC1.v);
    M2[j].v = fB2[j].v * k2a + (fB[j].v * k2b + IC2.v);
  }

  // ---- MFMA3/4: high parts of C and Q; fold in exact low-order f32 terms
  v4f Cc[2], Qc[2];
  #pragma unroll
  for (int j = 0; j < 2; ++j) {
    v4f c3m = __builtin_amdgcn_mfma_f32_16x16x32_f16(M1[j].v, fB2[j].v, z4, 0, 0, 0);
    v4f c4m = __builtin_amdgcn_mfma_f32_16x16x32_f16(M2[j].v, fB2[j].v, z4, 0, 0, 0);
    #pragma unroll
    for (int reg = 0; reg < 4; ++reg) {
      float dg = (4 * q + reg == nn) ? 1.f : 0.f;
      // Cc = (c4B^4+c3B^3+c2B^2) + B/2 + I + A   (I + A exact f32)
      Cc[j][reg] = fmaf(c3m[reg], 2.44140625e-4f,
                        fmaf(cB[j][reg], 0.25f, dg + Af[j][reg]));
      // Qr = Q - I = (q4B^4+q3B^3+q2B^2) + B/6
      Qc[j][reg] = fmaf(c4m[reg], 2.44140625e-4f, cB[j][reg] * 0.083333333f);
    }
  }

  // ---- transform 3: fQ = gather(Qr) (symmetric) ----
  V8U fQ[2];
  #pragma unroll
  for (int j = 0; j < 2; ++j) {
    PkU u0, u1;
    u0.h = __builtin_amdgcn_cvt_pkrtz(Qc[j][0], Qc[j][1]);
    u1.h = __builtin_amdgcn_cvt_pkrtz(Qc[j][2], Qc[j][3]);
    fQ[j].u[0] = __builtin_amdgcn_ds_bpermute(idxA, (int)u0.u);
    fQ[j].u[1] = __builtin_amdgcn_ds_bpermute(idxA, (int)u1.u);
    fQ[j].u[2] = __builtin_amdgcn_ds_bpermute(idxB, (int)u0.u);
    fQ[j].u[3] = __builtin_amdgcn_ds_bpermute(idxB, (int)u1.u);
  }

  // ---- MFMA5: E = Cc + A*Qr  (A-side f16-exact) ----
  v4f E[2];
  #pragma unroll
  for (int j = 0; j < 2; ++j) {
    v4f c5 = __builtin_amdgcn_mfma_f32_16x16x32_f16(Apk[j].v, fQ[j].v, z4, 0, 0, 0);
    E[j] = Cc[j] + c5 * 0.5f;
  }

  // ---- squarings: E <- E*E (A-side exact hi/lo via LDS row transpose) ----
  int smax = max(sv[0], sv[1]);
  for (int it = 0; it < smax; ++it) {
    #pragma unroll
    for (int j = 0; j < 2; ++j) {
      if (it < sv[j]) {
        float* Erp = ErB + j * 320;
        // B-side via bpermute of packed E
        PkU u0, u1;
        u0.h = __builtin_amdgcn_cvt_pkrtz(E[j][0], E[j][1]);
        u1.h = __builtin_amdgcn_cvt_pkrtz(E[j][2], E[j][3]);
        V8U bfe;
        bfe.u[0] = __builtin_amdgcn_ds_bpermute(idxA, (int)u0.u);
        bfe.u[1] = __builtin_amdgcn_ds_bpermute(idxA, (int)u1.u);
        bfe.u[2] = __builtin_amdgcn_ds_bpermute(idxB, (int)u0.u);
        bfe.u[3] = __builtin_amdgcn_ds_bpermute(idxB, (int)u1.u);
        // A-side: E rows via LDS
        #pragma unroll
        for (int reg = 0; reg < 4; ++reg)
          Erp[(4 * q + reg) * 20 + nn] = E[j][reg];
        asm volatile("s_waitcnt lgkmcnt(0)" ::: "memory");
        float4 a0 = *(const float4*)(Erp + nn * 20 + b8);
        float4 a1 = *(const float4*)(Erp + nn * 20 + b8 + 4);
        float xa[8] = {a0.x, a0.y, a0.z, a0.w, a1.x, a1.y, a1.z, a1.w};
        v8h ahi, alo;
        split8(xa, ahi, alo);
        v8h Ecat = (q < 2) ? ahi : alo;
        v4f z = {0.f, 0.f, 0.f, 0.f};
        E[j] = __builtin_amdgcn_mfma_f32_16x16x32_f16(Ecat, bfe.v, z, 0, 0, 0);
      }
    }
  }

  // ---- store T + fused attn-weighted transported partials ----
  float pacc[4] = {0.f, 0.f, 0.f, 0.f};
  #pragma unroll
  for (int j = 0; j < 2; ++j) {
    int p = pbase + j;
    float* dst = Tg + (size_t)p * 256;
    #pragma unroll
    for (int reg = 0; reg < 4; ++reg)
      dst[(4 * q + reg) * 16 + nn] = E[j][reg];
    int b = p >> 14, i = p & 127;
    float xv = xm[((b << 7) + i) * 16 + nn];
    float aw = attn[(size_t)p] * xv;
    #pragma unroll
    for (int reg = 0; reg < 4; ++reg)
      pacc[reg] = fmaf(aw, E[j][reg], pacc[reg]);
  }
  // reduce over column lanes (nn bits 0..3); row r = 4q+reg
  #pragma unroll
  for (int reg = 0; reg < 4; ++reg) {
    #pragma unroll
    for (int off = 1; off < 16; off <<= 1)
      pacc[reg] += __shfl_xor(pacc[reg], off, 64);
  }
  if (nn == 0) {
    #pragma unroll
    for (int reg = 0; reg < 4; ++reg) sred[wu][4 * q + reg] = pacc[reg];
  }
  __syncthreads();
  if (t < 16)
    part[(size_t)blockIdx.x * 16 + t] =
        sred[0][t] + sred[1][t] + sred[2][t] + sred[3][t];
}

// ---------------------------------------------------------------------------
// K5: settled[bj] = sum of 16 per-block partials; out = settled @ Wo^T + bo
// ---------------------------------------------------------------------------
__global__ __launch_bounds__(64) void settle_fin_kernel(
    const float* __restrict__ part, const float* __restrict__ Wo,
    const float* __restrict__ bo, float* __restrict__ outp) {
  int bj = blockIdx.x, t = threadIdx.x;
  int r = t & 15, e0 = t >> 4;
  const float* pb = part + (size_t)bj * 256;
  float s = pb[e0 * 16 + r] + pb[(e0 + 4) * 16 + r] +
            pb[(e0 + 8) * 16 + r] + pb[(e0 + 12) * 16 + r];
  __shared__ float sf[64];
  sf[t] = s;
  __syncthreads();
  if (t < 16) sf[t] = sf[t] + sf[16 + t] + sf[32 + t] + sf[48 + t];
  __syncthreads();
  if (t < 16) {
    float o = bo[t];
    const float* wr = Wo + t * 16;
    #pragma unroll
    for (int c = 0; c < 16; ++c) o = fmaf(wr[c], sf[c], o);
    outp[bj * 16 + t] = o;
  }
}

// ---------------------------------------------------------------------------
extern "C" void kernel_launch(void* const* d_in, const int* in_sizes, int n_in,
                              void* d_out, int out_size, void* d_ws,
                              size_t ws_size, hipStream_t stream) {
  const float* xl = (const float*)d_in[0];
  const float* xm = (const float*)d_in[1];
  const float* Wq = (const float*)d_in[2];
  const float* bq = (const float*)d_in[3];
  const float* Wk = (const float*)d_in[4];
  const float* bk = (const float*)d_in[5];
  const float* W1 = (const float*)d_in[6];
  const float* b1 = (const float*)d_in[7];
  const float* W2 = (const float*)d_in[8];
  const float* b2 = (const float*)d_in[9];
  const float* Wo = (const float*)d_in[10];
  const float* bo = (const float*)d_in[11];
  float* outp = (float*)d_out;
  float* Tg = outp + 8192;  // [65536][256]: h f16 (bytes 0..511) + lie f16
                            // (bytes 512..751) per slot, then T fp32
  float* wsf = (float*)d_ws;
  float* Q = wsf;
  float* K = wsf + 65536;
  float* attn = wsf + 131072;
  float* part = wsf + 196608;  // [8192][16] f32 partial settled sums

  hipLaunchKernelGGL(qk_kernel, dim3(512), dim3(128), 0, stream, xl, Wq, bq, Wk, bk, Q, K);
  hipLaunchKernelGGL(attn_kernel, dim3(512), dim3(128), 0, stream, Q, K, attn);
  hipLaunchKernelGGL(h_kernel, dim3(1024), dim3(256), 0, stream, xl, W1, b1, (__half*)Tg);
  hipLaunchKernelGGL(lie_kernel, dim3(1024), dim3(256), 0, stream, W2, b2, Tg);
  hipLaunchKernelGGL(expm_kernel, dim3(8192), dim3(256), 0, stream, Tg, attn, xm, part);
  hipLaunchKernelGGL(settle_fin_kernel, dim3(512), dim3(64), 0, stream, part, Wo, bo, outp);
}